// Round 6
// baseline (405.930 us; speedup 1.0000x reference)
//
#include <hip/hip_runtime.h>
#include <cstdint>
#include <cstddef>

#define B_SZ 4
#define T_SZ 2048
#define NH 16
#define HD 64
#define CD 1024
#define MROWS (B_SZ*T_SZ)
#define NEG_BIG (-1e30f)
// 0.125 (1/sqrt(64)) * log2(e): fold softmax base-2 conversion into Q prescale
#define Q_SCALE 0.180336880f

typedef __bf16 bf16x8 __attribute__((ext_vector_type(8)));
typedef __bf16 bf16x4 __attribute__((ext_vector_type(4)));
typedef short s16x4 __attribute__((ext_vector_type(4)));
typedef float f32x4 __attribute__((ext_vector_type(4)));

typedef __attribute__((address_space(3))) void* as3p;
typedef const __attribute__((address_space(1))) void* as1p;

__device__ __forceinline__ void glds16(const void* g, void* l) {
  __builtin_amdgcn_global_load_lds((as1p)g, (as3p)l, 16, 0, 0);
}

// ---------------------------------------------------------------------------
// Dtype discriminator (fp32 vs bf16 input encoding). flag=1 -> bf16.
// ---------------------------------------------------------------------------
__global__ __launch_bounds__(256) void detect_dtype(const uint32_t* __restrict__ x,
                                                    int* __restrict__ flag) {
  __shared__ int cnt[256];
  const int t = threadIdx.x;
  int c = 0;
  for (int i = 0; i < 4; i++) {
    uint32_t w = x[t * 4 + i];
    uint32_t e = (w >> 7) & 0xFF;
    c += (e >= 100 && e <= 140) ? 1 : 0;
  }
  cnt[t] = c;
  __syncthreads();
  for (int s = 128; s > 0; s >>= 1) {
    if (t < s) cnt[t] += cnt[t + s];
    __syncthreads();
  }
  if (t == 0) flag[0] = (cnt[0] > 700) ? 1 : 0;
}

__device__ __forceinline__ bf16x8 cvt8(const void* src, int isbf, size_t i8) {
  bf16x8 o;
  if (isbf) {
    o = ((const bf16x8*)src)[i8];
  } else {
    const float4* s = (const float4*)((const float*)src + i8 * 8);
    float4 a = s[0], b = s[1];
    o[0] = (__bf16)a.x; o[1] = (__bf16)a.y; o[2] = (__bf16)a.z; o[3] = (__bf16)a.w;
    o[4] = (__bf16)b.x; o[5] = (__bf16)b.y; o[6] = (__bf16)b.z; o[7] = (__bf16)b.w;
  }
  return o;
}

__global__ __launch_bounds__(256) void conv_in(const void* __restrict__ src,
                                               const int* __restrict__ flag,
                                               __bf16* __restrict__ dst, int n8) {
  int i = blockIdx.x * 256 + threadIdx.x;
  if (i >= n8) return;
  ((bf16x8*)dst)[i] = cvt8(src, flag[0], i);
}

struct Ptr4 { const void* s[4]; __bf16* d[4]; };

__global__ __launch_bounds__(256) void conv_b4(Ptr4 p, const int* __restrict__ flag) {
  int i = threadIdx.x;
  if (i >= CD / 8) return;
  int which = blockIdx.x;
  ((bf16x8*)p.d[which])[i] = cvt8(p.s[which], flag[0], i);
}

// 4 weight matrices 1024x1024 -> transposed canonical bf16 (z selects)
__global__ __launch_bounds__(256) void transpose_conv4(Ptr4 p,
                                                       const int* __restrict__ flag) {
  __shared__ __align__(16) __bf16 tile[64 * 72];
  const void* W = p.s[blockIdx.z];
  __bf16* WT = p.d[blockIdx.z];
  const int t = threadIdx.x;
  const int r0 = blockIdx.y * 64, c0 = blockIdx.x * 64;
  const int rr = t >> 3, c8 = (t & 7) * 8;
  const int isbf = flag[0];
  for (int pp = 0; pp < 2; pp++) {
    int r = pp * 32 + rr;
    *(bf16x8*)(tile + r * 72 + c8) =
        cvt8(W, isbf, ((size_t)(r0 + r) * CD + c0 + c8) / 8);
  }
  __syncthreads();
  for (int pp = 0; pp < 2; pp++) {
    int cc = pp * 32 + rr;
    bf16x8 o;
    for (int j = 0; j < 8; j++) o[j] = tile[(c8 + j) * 72 + cc];
    *(bf16x8*)(WT + (size_t)(c0 + cc) * CD + r0 + c8) = o;
  }
}

// ---------------------------------------------------------------------------
// Fused QKV GEMM: C[8192, 3072] = x @ [WqT;WkT;WvT]^T + bias.
// Epilogue routes by col segment: 0-1023 -> Qb (scaled, [B,H,T,64]),
// 1024-2047 -> Kb ([B,H,T,64]), 2048-3071 -> Vt ([B*H, 64, T]).
// ---------------------------------------------------------------------------
__global__ __launch_bounds__(256) void gemm_qkv(
    const __bf16* __restrict__ A, const __bf16* __restrict__ BT,
    const __bf16* __restrict__ bias,
    __bf16* __restrict__ Qb, __bf16* __restrict__ Kb, __bf16* __restrict__ Vt) {
  __shared__ __align__(16) __bf16 As[128 * 64];
  __shared__ __align__(16) __bf16 Bs[128 * 64];
  const int tid = threadIdx.x;
  const int w = tid >> 6, lane = tid & 63;
  const int l15 = lane & 15, quad = lane >> 4;
  const int wm = w & 1, wn = w >> 1;
  const int bm = blockIdx.y, bn = blockIdx.x;

  f32x4 acc[4][4];
  for (int i = 0; i < 4; i++)
    for (int j = 0; j < 4; j++) acc[i][j] = (f32x4)0.f;

  const int srow = lane >> 3, scol = (lane & 7) * 8;
  const __bf16* Abase = A + (size_t)(bm * 128) * CD;
  const __bf16* Bbase = BT + (size_t)(bn * 128) * CD;

  for (int k0 = 0; k0 < CD; k0 += 64) {
    __syncthreads();
    for (int p = 0; p < 4; p++) {
      int seg = p * 4 + w;
      int row = seg * 8 + srow;
      glds16(Abase + (size_t)row * CD + k0 + scol, (char*)As + seg * 1024);
      glds16(Bbase + (size_t)row * CD + k0 + scol, (char*)Bs + seg * 1024);
    }
    __syncthreads();
    for (int kc = 0; kc < 2; kc++) {
      const int koff = kc * 32 + quad * 8;
      bf16x8 af[4], bfr[4];
      for (int mt = 0; mt < 4; mt++)
        af[mt] = *(const bf16x8*)(As + (wm * 64 + mt * 16 + l15) * 64 + koff);
      for (int nt = 0; nt < 4; nt++)
        bfr[nt] = *(const bf16x8*)(Bs + (wn * 64 + nt * 16 + l15) * 64 + koff);
      for (int mt = 0; mt < 4; mt++)
        for (int nt = 0; nt < 4; nt++)
          acc[mt][nt] = __builtin_amdgcn_mfma_f32_16x16x32_bf16(
              af[mt], bfr[nt], acc[mt][nt], 0, 0, 0);
    }
  }

  for (int nt = 0; nt < 4; nt++) {
    int col = bn * 128 + wn * 64 + nt * 16 + l15;
    int seg = col >> 10;            // 0=Q 1=K 2=V (uniform per nt)
    int c = col & 1023, h = c >> 6, d = c & 63;
    float bv = (float)bias[col];
    for (int mt = 0; mt < 4; mt++) {
      int row0 = bm * 128 + wm * 64 + mt * 16 + quad * 4;
      int b = row0 >> 11, tok0 = row0 & 2047;
      if (seg == 2) {
        bf16x4 o;
        for (int r = 0; r < 4; r++) o[r] = (__bf16)(acc[mt][nt][r] + bv);
        *(bf16x4*)(Vt + ((size_t)((b << 4) + h) * HD + d) * T_SZ + tok0) = o;
      } else {
        __bf16* dst = (seg == 0) ? Qb : Kb;
        float sc = (seg == 0) ? Q_SCALE : 1.f;
        for (int r = 0; r < 4; r++) {
          float v = (acc[mt][nt][r] + bv) * sc;
          dst[((size_t)(b * NH + h) * T_SZ + tok0 + r) * HD + d] = (__bf16)v;
        }
      }
    }
  }
}

// ---------------------------------------------------------------------------
// Out-proj GEMM: d_out[8192,1024] = Yb @ WoT^T + bo, output dtype per flag.
// ---------------------------------------------------------------------------
__global__ __launch_bounds__(256) void gemm_out(
    const __bf16* __restrict__ A, const __bf16* __restrict__ BT,
    const __bf16* __restrict__ bias, void* __restrict__ Out,
    const int* __restrict__ flag) {
  __shared__ __align__(16) __bf16 As[128 * 64];
  __shared__ __align__(16) __bf16 Bs[128 * 64];
  const int tid = threadIdx.x;
  const int w = tid >> 6, lane = tid & 63;
  const int l15 = lane & 15, quad = lane >> 4;
  const int wm = w & 1, wn = w >> 1;
  const int bm = blockIdx.y, bn = blockIdx.x;

  f32x4 acc[4][4];
  for (int i = 0; i < 4; i++)
    for (int j = 0; j < 4; j++) acc[i][j] = (f32x4)0.f;

  const int srow = lane >> 3, scol = (lane & 7) * 8;
  const __bf16* Abase = A + (size_t)(bm * 128) * CD;
  const __bf16* Bbase = BT + (size_t)(bn * 128) * CD;

  for (int k0 = 0; k0 < CD; k0 += 64) {
    __syncthreads();
    for (int p = 0; p < 4; p++) {
      int seg = p * 4 + w;
      int row = seg * 8 + srow;
      glds16(Abase + (size_t)row * CD + k0 + scol, (char*)As + seg * 1024);
      glds16(Bbase + (size_t)row * CD + k0 + scol, (char*)Bs + seg * 1024);
    }
    __syncthreads();
    for (int kc = 0; kc < 2; kc++) {
      const int koff = kc * 32 + quad * 8;
      bf16x8 af[4], bfr[4];
      for (int mt = 0; mt < 4; mt++)
        af[mt] = *(const bf16x8*)(As + (wm * 64 + mt * 16 + l15) * 64 + koff);
      for (int nt = 0; nt < 4; nt++)
        bfr[nt] = *(const bf16x8*)(Bs + (wn * 64 + nt * 16 + l15) * 64 + koff);
      for (int mt = 0; mt < 4; mt++)
        for (int nt = 0; nt < 4; nt++)
          acc[mt][nt] = __builtin_amdgcn_mfma_f32_16x16x32_bf16(
              af[mt], bfr[nt], acc[mt][nt], 0, 0, 0);
    }
  }

  const int isbf = flag[0];
  for (int nt = 0; nt < 4; nt++) {
    int col = bn * 128 + wn * 64 + nt * 16 + l15;
    float bv = (float)bias[col];
    for (int mt = 0; mt < 4; mt++) {
      int row0 = bm * 128 + wm * 64 + mt * 16 + quad * 4;
      if (isbf) {
        for (int r = 0; r < 4; r++)
          ((__bf16*)Out)[(size_t)(row0 + r) * CD + col] =
              (__bf16)(acc[mt][nt][r] + bv);
      } else {
        for (int r = 0; r < 4; r++)
          ((float*)Out)[(size_t)(row0 + r) * CD + col] = acc[mt][nt][r] + bv;
      }
    }
  }
}

// ---------------------------------------------------------------------------
// Flash attention, causal, transposed-S. Q pre-scaled by 0.125*log2e.
// Q/K: [B*H, T, 64]; Vt: [B*H, 64, T]. One q-tile (128 rows) per block;
// grid.x=16 with interleaved heavy/light mapping so any 4 consecutive
// blocks carry equal total KV-iters; grid=1024 blocks = 4/CU all-resident.
// ---------------------------------------------------------------------------
__global__ __launch_bounds__(256) void attn(
    const __bf16* __restrict__ Q, const __bf16* __restrict__ K,
    const __bf16* __restrict__ Vt, __bf16* __restrict__ Y) {
  __shared__ __align__(16) __bf16 Ks[2][64 * 72];
  __shared__ __align__(16) __bf16 Vs[2][64 * 72];   // [d][key]

  const int tid = threadIdx.x, w = tid >> 6, lane = tid & 63;
  const int l15 = lane & 15, quad = lane >> 4;
  const int bh = blockIdx.y;
  const int bx = blockIdx.x;
  const int tq = (bx & 1) ? (bx >> 1) : (15 - (bx >> 1));
  const int q0 = tq * 128;
  const int niter = 2 * tq + 2;

  const __bf16* Qbh = Q + (size_t)bh * T_SZ * HD;
  const __bf16* Kbh = K + (size_t)bh * T_SZ * HD;
  const __bf16* Vbh = Vt + (size_t)bh * HD * T_SZ;

  const int srow = tid >> 2;          // 0..63
  const int scol = (tid & 3) * 8;     // 0,8,16,24
  const int b = bh >> 4, h = bh & 15;

  // prologue: stage KV tile 0 into buffer 0
  for (int p = 0; p < 2; p++) {
    int c = scol + p * 32;
    *(bf16x8*)(Ks[0] + srow * 72 + c) = *(const bf16x8*)(Kbh + (size_t)srow * HD + c);
    *(bf16x8*)(Vs[0] + srow * 72 + c) = *(const bf16x8*)(Vbh + (size_t)srow * T_SZ + c);
  }

  // Q fragments (B-operand: n=l15->q, k=quad*8+j->d)
  bf16x8 aq[2][2];
  for (int mt = 0; mt < 2; mt++)
    for (int kc = 0; kc < 2; kc++)
      aq[mt][kc] = *(const bf16x8*)(
          Qbh + (size_t)(q0 + w * 32 + mt * 16 + l15) * HD + kc * 32 + quad * 8);

  f32x4 acco[2][4];     // O^T tiles [d16 x q16]: row d=quad*4+r, col q=l15
  for (int mt = 0; mt < 2; mt++)
    for (int dt = 0; dt < 4; dt++) acco[mt][dt] = (f32x4)0.f;
  float m_[2], l_[2];
  for (int mt = 0; mt < 2; mt++) { m_[mt] = NEG_BIG; l_[mt] = 0.f; }

  for (int it = 0; it < niter; it++) {
    const int cur = it & 1;
    const int kv0 = it * 64;
    __syncthreads();

    // prefetch next KV tile into regs (overlaps compute)
    bf16x8 kn[2], vn[2];
    const bool havenext = (it + 1 < niter);
    if (havenext) {
      int kv1 = kv0 + 64;
      for (int p = 0; p < 2; p++) {
        int c = scol + p * 32;
        kn[p] = *(const bf16x8*)(Kbh + (size_t)(kv1 + srow) * HD + c);
        vn[p] = *(const bf16x8*)(Vbh + (size_t)srow * T_SZ + kv1 + c);
      }
    }

    const __bf16* Ksc = Ks[cur];
    const __bf16* Vsc = Vs[cur];

    // S^T = K Q^T : tiles [key16 x q16]; row key=quad*4+r, col q=l15
    f32x4 accs[2][4];
    for (int mt = 0; mt < 2; mt++)
      for (int nt = 0; nt < 4; nt++) accs[mt][nt] = (f32x4)0.f;
    for (int kc = 0; kc < 2; kc++)
      for (int nt = 0; nt < 4; nt++) {
        bf16x8 ak = *(const bf16x8*)(Ksc + (nt * 16 + l15) * 72 + kc * 32 + quad * 8);
        for (int mt = 0; mt < 2; mt++)
          accs[mt][nt] = __builtin_amdgcn_mfma_f32_16x16x32_bf16(
              ak, aq[mt][kc], accs[mt][nt], 0, 0, 0);
      }

    // causal mask
    for (int mt = 0; mt < 2; mt++) {
      int qg = q0 + w * 32 + mt * 16 + l15;
      if (kv0 + 63 > q0 + w * 32 + mt * 16) {
        for (int nt = 0; nt < 4; nt++) {
          int kg0 = kv0 + nt * 16 + quad * 4;
          for (int r = 0; r < 4; r++)
            if (kg0 + r > qg) accs[mt][nt][r] = NEG_BIG;
        }
      }
    }

    // online softmax over keys (rows + cross-quad)
    float mloc[2], alpha[2], rs[2];
    for (int mt = 0; mt < 2; mt++) {
      float a0 = fmaxf(fmaxf(accs[mt][0][0], accs[mt][0][1]),
                       fmaxf(accs[mt][0][2], accs[mt][0][3]));
      float a1 = fmaxf(fmaxf(accs[mt][1][0], accs[mt][1][1]),
                       fmaxf(accs[mt][1][2], accs[mt][1][3]));
      float a2 = fmaxf(fmaxf(accs[mt][2][0], accs[mt][2][1]),
                       fmaxf(accs[mt][2][2], accs[mt][2][3]));
      float a3 = fmaxf(fmaxf(accs[mt][3][0], accs[mt][3][1]),
                       fmaxf(accs[mt][3][2], accs[mt][3][3]));
      mloc[mt] = fmaxf(fmaxf(a0, a1), fmaxf(a2, a3));
    }
    for (int off = 16; off < 64; off <<= 1)
      for (int mt = 0; mt < 2; mt++)
        mloc[mt] = fmaxf(mloc[mt], __shfl_xor(mloc[mt], off));
    for (int mt = 0; mt < 2; mt++) {
      float mnew = fmaxf(m_[mt], mloc[mt]);
      alpha[mt] = exp2f(m_[mt] - mnew);
      m_[mt] = mnew;
      rs[mt] = 0.f;
    }

    // P^T = exp2(S^T - m): stays in regs as x16 B-operand fragments
    bf16x4 pf[2][4];
    for (int mt = 0; mt < 2; mt++)
      for (int nt = 0; nt < 4; nt++) {
        for (int r = 0; r < 4; r++) {
          float p = exp2f(accs[mt][nt][r] - m_[mt]);
          rs[mt] += p;
          pf[mt][nt][r] = (__bf16)p;
        }
      }
    for (int off = 16; off < 64; off <<= 1)
      for (int mt = 0; mt < 2; mt++) rs[mt] += __shfl_xor(rs[mt], off);
    for (int mt = 0; mt < 2; mt++) l_[mt] = l_[mt] * alpha[mt] + rs[mt];
    for (int mt = 0; mt < 2; mt++)
      for (int dt = 0; dt < 4; dt++)
        for (int r = 0; r < 4; r++) acco[mt][dt][r] *= alpha[mt];

    // O^T += V^T P^T  (x16 MFMA; A from Vs, B from regs)
    for (int nt = 0; nt < 4; nt++)
      for (int dt = 0; dt < 4; dt++) {
        bf16x4 av = *(const bf16x4*)(Vsc + (dt * 16 + l15) * 72 + nt * 16 + quad * 4);
        for (int mt = 0; mt < 2; mt++)
          acco[mt][dt] = __builtin_amdgcn_mfma_f32_16x16x16bf16_1k(
              *(const s16x4*)&av, *(const s16x4*)&pf[mt][nt], acco[mt][dt], 0, 0, 0);
      }

    // stage prefetched tile into the other buffer
    if (havenext) {
      int nb = cur ^ 1;
      for (int p = 0; p < 2; p++) {
        int c = scol + p * 32;
        *(bf16x8*)(Ks[nb] + srow * 72 + c) = kn[p];
        *(bf16x8*)(Vs[nb] + srow * 72 + c) = vn[p];
      }
    }
  }

  // epilogue: O^T -> Y [B*T, 1024], 8B stores (4 consecutive d)
  for (int mt = 0; mt < 2; mt++) {
    float rcp = 1.f / l_[mt];
    int qg = q0 + w * 32 + mt * 16 + l15;
    size_t base = ((size_t)(b * T_SZ + qg)) * CD + h * HD + quad * 4;
    for (int dt = 0; dt < 4; dt++) {
      bf16x4 o;
      for (int r = 0; r < 4; r++) o[r] = (__bf16)(acco[mt][dt][r] * rcp);
      *(bf16x4*)(Y + base + dt * 16) = o;
    }
  }
}

// ---------------------------------------------------------------------------
extern "C" void kernel_launch(void* const* d_in, const int* in_sizes, int n_in,
                              void* d_out, int out_size, void* d_ws, size_t ws_size,
                              hipStream_t stream) {
  (void)in_sizes; (void)n_in; (void)out_size; (void)ws_size;
  const void* x  = d_in[0];
  const void* Wq = d_in[2];
  const void* bq = d_in[3];
  const void* Wk = d_in[4];
  const void* bk = d_in[5];
  const void* Wv = d_in[6];
  const void* bv = d_in[7];
  const void* Wo = d_in[8];
  const void* bo = d_in[9];

  char* ws = (char*)d_ws;
  const size_t MB = 1024 * 1024;
  __bf16* WqkvT = (__bf16*)(ws + 0 * MB);          // [3072, 1024]
  __bf16* WoT   = (__bf16*)(ws + 6 * MB);
  __bf16* bqkvc = (__bf16*)(ws + 8 * MB);          // [3072]
  __bf16* boc   = (__bf16*)(ws + 8 * MB + 8192);
  int*    flag  = (int*)   (ws + 8 * MB + 65536);
  __bf16* xc    = (__bf16*)(ws + 9 * MB);          // [8192,1024]; reused as Yb
  __bf16* Qb    = (__bf16*)(ws + 25 * MB);         // [B*H,T,64] pre-scaled
  __bf16* Kb    = (__bf16*)(ws + 41 * MB);
  __bf16* Vt_g  = (__bf16*)(ws + 57 * MB);         // [B*H,64,T]
  __bf16* Yb    = xc;                              // xc dead after QKV GEMM

  dim3 tb(256);
  detect_dtype<<<1, tb, 0, stream>>>((const uint32_t*)x, flag);

  conv_in<<<4096, tb, 0, stream>>>(x, flag, xc, MROWS * CD / 8);
  Ptr4 pb = {{bq, bk, bv, bo}, {bqkvc, bqkvc + CD, bqkvc + 2 * CD, boc}};
  conv_b4<<<4, tb, 0, stream>>>(pb, flag);
  Ptr4 pw = {{Wq, Wk, Wv, Wo},
             {WqkvT, WqkvT + (size_t)CD * CD, WqkvT + 2 * (size_t)CD * CD, WoT}};
  transpose_conv4<<<dim3(16, 16, 4), tb, 0, stream>>>(pw, flag);

  gemm_qkv<<<dim3(24, MROWS / 128), tb, 0, stream>>>(xc, WqkvT, bqkvc, Qb, Kb, Vt_g);

  attn<<<dim3(16, B_SZ * NH), tb, 0, stream>>>(Qb, Kb, Vt_g, Yb);

  gemm_out<<<dim3(CD / 128, MROWS / 128), tb, 0, stream>>>(Yb, WoT, boc, d_out, flag);
}

// Round 7
// 346.162 us; speedup vs baseline: 1.1727x; 1.1727x over previous
//
#include <hip/hip_runtime.h>
#include <cstdint>
#include <cstddef>

#define B_SZ 4
#define T_SZ 2048
#define NH 16
#define HD 64
#define CD 1024
#define MROWS (B_SZ*T_SZ)
#define NEG_BIG (-1e30f)
// 0.125 (1/sqrt(64)) * log2(e): fold softmax base-2 conversion into Q prescale
#define Q_SCALE 0.180336880f

typedef __bf16 bf16x8 __attribute__((ext_vector_type(8)));
typedef __bf16 bf16x4 __attribute__((ext_vector_type(4)));
typedef short s16x4 __attribute__((ext_vector_type(4)));
typedef float f32x4 __attribute__((ext_vector_type(4)));

typedef __attribute__((address_space(3))) void* as3p;
typedef const __attribute__((address_space(1))) void* as1p;

__device__ __forceinline__ void glds16(const void* g, void* l) {
  __builtin_amdgcn_global_load_lds((as1p)g, (as3p)l, 16, 0, 0);
}

// ---------------------------------------------------------------------------
// Dtype discriminator (fp32 vs bf16 input encoding). flag=1 -> bf16.
// ---------------------------------------------------------------------------
__global__ __launch_bounds__(256) void detect_dtype(const uint32_t* __restrict__ x,
                                                    int* __restrict__ flag) {
  __shared__ int cnt[256];
  const int t = threadIdx.x;
  int c = 0;
  for (int i = 0; i < 4; i++) {
    uint32_t w = x[t * 4 + i];
    uint32_t e = (w >> 7) & 0xFF;
    c += (e >= 100 && e <= 140) ? 1 : 0;
  }
  cnt[t] = c;
  __syncthreads();
  for (int s = 128; s > 0; s >>= 1) {
    if (t < s) cnt[t] += cnt[t + s];
    __syncthreads();
  }
  if (t == 0) flag[0] = (cnt[0] > 700) ? 1 : 0;
}

__device__ __forceinline__ bf16x8 cvt8(const void* src, int isbf, size_t i8) {
  bf16x8 o;
  if (isbf) {
    o = ((const bf16x8*)src)[i8];
  } else {
    const float4* s = (const float4*)((const float*)src + i8 * 8);
    float4 a = s[0], b = s[1];
    o[0] = (__bf16)a.x; o[1] = (__bf16)a.y; o[2] = (__bf16)a.z; o[3] = (__bf16)a.w;
    o[4] = (__bf16)b.x; o[5] = (__bf16)b.y; o[6] = (__bf16)b.z; o[7] = (__bf16)b.w;
  }
  return o;
}

__global__ __launch_bounds__(256) void conv_in(const void* __restrict__ src,
                                               const int* __restrict__ flag,
                                               __bf16* __restrict__ dst, int n8) {
  int i = blockIdx.x * 256 + threadIdx.x;
  if (i >= n8) return;
  ((bf16x8*)dst)[i] = cvt8(src, flag[0], i);
}

struct Ptr4 { const void* s[4]; __bf16* d[4]; };

__global__ __launch_bounds__(256) void conv_b4(Ptr4 p, const int* __restrict__ flag) {
  int i = threadIdx.x;
  if (i >= CD / 8) return;
  int which = blockIdx.x;
  ((bf16x8*)p.d[which])[i] = cvt8(p.s[which], flag[0], i);
}

// 4 weight matrices 1024x1024 -> transposed canonical bf16 (z selects)
__global__ __launch_bounds__(256) void transpose_conv4(Ptr4 p,
                                                       const int* __restrict__ flag) {
  __shared__ __align__(16) __bf16 tile[64 * 72];
  const void* W = p.s[blockIdx.z];
  __bf16* WT = p.d[blockIdx.z];
  const int t = threadIdx.x;
  const int r0 = blockIdx.y * 64, c0 = blockIdx.x * 64;
  const int rr = t >> 3, c8 = (t & 7) * 8;
  const int isbf = flag[0];
  for (int pp = 0; pp < 2; pp++) {
    int r = pp * 32 + rr;
    *(bf16x8*)(tile + r * 72 + c8) =
        cvt8(W, isbf, ((size_t)(r0 + r) * CD + c0 + c8) / 8);
  }
  __syncthreads();
  for (int pp = 0; pp < 2; pp++) {
    int cc = pp * 32 + rr;
    bf16x8 o;
    for (int j = 0; j < 8; j++) o[j] = tile[(c8 + j) * 72 + cc];
    *(bf16x8*)(WT + (size_t)(c0 + cc) * CD + r0 + c8) = o;
  }
}

// ---------------------------------------------------------------------------
// Fused QKV GEMM: C[8192, 3072] = x @ [WqT;WkT;WvT]^T + bias.
// Epilogue routes by col segment: 0-1023 -> Qb (scaled, [B,H,T,64]),
// 1024-2047 -> Kb ([B,H,T,64]), 2048-3071 -> Vt ([B*H, 64, T]).
// ---------------------------------------------------------------------------
__global__ __launch_bounds__(256) void gemm_qkv(
    const __bf16* __restrict__ A, const __bf16* __restrict__ BT,
    const __bf16* __restrict__ bias,
    __bf16* __restrict__ Qb, __bf16* __restrict__ Kb, __bf16* __restrict__ Vt) {
  __shared__ __align__(16) __bf16 As[128 * 64];
  __shared__ __align__(16) __bf16 Bs[128 * 64];
  const int tid = threadIdx.x;
  const int w = tid >> 6, lane = tid & 63;
  const int l15 = lane & 15, quad = lane >> 4;
  const int wm = w & 1, wn = w >> 1;
  const int bm = blockIdx.y, bn = blockIdx.x;

  f32x4 acc[4][4];
  for (int i = 0; i < 4; i++)
    for (int j = 0; j < 4; j++) acc[i][j] = (f32x4)0.f;

  const int srow = lane >> 3, scol = (lane & 7) * 8;
  const __bf16* Abase = A + (size_t)(bm * 128) * CD;
  const __bf16* Bbase = BT + (size_t)(bn * 128) * CD;

  for (int k0 = 0; k0 < CD; k0 += 64) {
    __syncthreads();
    for (int p = 0; p < 4; p++) {
      int seg = p * 4 + w;
      int row = seg * 8 + srow;
      glds16(Abase + (size_t)row * CD + k0 + scol, (char*)As + seg * 1024);
      glds16(Bbase + (size_t)row * CD + k0 + scol, (char*)Bs + seg * 1024);
    }
    __syncthreads();
    for (int kc = 0; kc < 2; kc++) {
      const int koff = kc * 32 + quad * 8;
      bf16x8 af[4], bfr[4];
      for (int mt = 0; mt < 4; mt++)
        af[mt] = *(const bf16x8*)(As + (wm * 64 + mt * 16 + l15) * 64 + koff);
      for (int nt = 0; nt < 4; nt++)
        bfr[nt] = *(const bf16x8*)(Bs + (wn * 64 + nt * 16 + l15) * 64 + koff);
      for (int mt = 0; mt < 4; mt++)
        for (int nt = 0; nt < 4; nt++)
          acc[mt][nt] = __builtin_amdgcn_mfma_f32_16x16x32_bf16(
              af[mt], bfr[nt], acc[mt][nt], 0, 0, 0);
    }
  }

  for (int nt = 0; nt < 4; nt++) {
    int col = bn * 128 + wn * 64 + nt * 16 + l15;
    int seg = col >> 10;            // 0=Q 1=K 2=V (uniform per nt)
    int c = col & 1023, h = c >> 6, d = c & 63;
    float bv = (float)bias[col];
    for (int mt = 0; mt < 4; mt++) {
      int row0 = bm * 128 + wm * 64 + mt * 16 + quad * 4;
      int b = row0 >> 11, tok0 = row0 & 2047;
      if (seg == 2) {
        bf16x4 o;
        for (int r = 0; r < 4; r++) o[r] = (__bf16)(acc[mt][nt][r] + bv);
        *(bf16x4*)(Vt + ((size_t)((b << 4) + h) * HD + d) * T_SZ + tok0) = o;
      } else {
        __bf16* dst = (seg == 0) ? Qb : Kb;
        float sc = (seg == 0) ? Q_SCALE : 1.f;
        for (int r = 0; r < 4; r++) {
          float v = (acc[mt][nt][r] + bv) * sc;
          dst[((size_t)(b * NH + h) * T_SZ + tok0 + r) * HD + d] = (__bf16)v;
        }
      }
    }
  }
}

// ---------------------------------------------------------------------------
// Out-proj GEMM: d_out[8192,1024] = Yb @ WoT^T + bo, output dtype per flag.
// ---------------------------------------------------------------------------
__global__ __launch_bounds__(256) void gemm_out(
    const __bf16* __restrict__ A, const __bf16* __restrict__ BT,
    const __bf16* __restrict__ bias, void* __restrict__ Out,
    const int* __restrict__ flag) {
  __shared__ __align__(16) __bf16 As[128 * 64];
  __shared__ __align__(16) __bf16 Bs[128 * 64];
  const int tid = threadIdx.x;
  const int w = tid >> 6, lane = tid & 63;
  const int l15 = lane & 15, quad = lane >> 4;
  const int wm = w & 1, wn = w >> 1;
  const int bm = blockIdx.y, bn = blockIdx.x;

  f32x4 acc[4][4];
  for (int i = 0; i < 4; i++)
    for (int j = 0; j < 4; j++) acc[i][j] = (f32x4)0.f;

  const int srow = lane >> 3, scol = (lane & 7) * 8;
  const __bf16* Abase = A + (size_t)(bm * 128) * CD;
  const __bf16* Bbase = BT + (size_t)(bn * 128) * CD;

  for (int k0 = 0; k0 < CD; k0 += 64) {
    __syncthreads();
    for (int p = 0; p < 4; p++) {
      int seg = p * 4 + w;
      int row = seg * 8 + srow;
      glds16(Abase + (size_t)row * CD + k0 + scol, (char*)As + seg * 1024);
      glds16(Bbase + (size_t)row * CD + k0 + scol, (char*)Bs + seg * 1024);
    }
    __syncthreads();
    for (int kc = 0; kc < 2; kc++) {
      const int koff = kc * 32 + quad * 8;
      bf16x8 af[4], bfr[4];
      for (int mt = 0; mt < 4; mt++)
        af[mt] = *(const bf16x8*)(As + (wm * 64 + mt * 16 + l15) * 64 + koff);
      for (int nt = 0; nt < 4; nt++)
        bfr[nt] = *(const bf16x8*)(Bs + (wn * 64 + nt * 16 + l15) * 64 + koff);
      for (int mt = 0; mt < 4; mt++)
        for (int nt = 0; nt < 4; nt++)
          acc[mt][nt] = __builtin_amdgcn_mfma_f32_16x16x32_bf16(
              af[mt], bfr[nt], acc[mt][nt], 0, 0, 0);
    }
  }

  const int isbf = flag[0];
  for (int nt = 0; nt < 4; nt++) {
    int col = bn * 128 + wn * 64 + nt * 16 + l15;
    float bv = (float)bias[col];
    for (int mt = 0; mt < 4; mt++) {
      int row0 = bm * 128 + wm * 64 + mt * 16 + quad * 4;
      if (isbf) {
        for (int r = 0; r < 4; r++)
          ((__bf16*)Out)[(size_t)(row0 + r) * CD + col] =
              (__bf16)(acc[mt][nt][r] + bv);
      } else {
        for (int r = 0; r < 4; r++)
          ((float*)Out)[(size_t)(row0 + r) * CD + col] = acc[mt][nt][r] + bv;
      }
    }
  }
}

// ---------------------------------------------------------------------------
// Flash attention, causal, transposed-S. Q pre-scaled by 0.125*log2e.
// Q/K: [B*H, T, 64]; Vt: [B*H, 64, T].
// Q-tile 64 rows (16 q-rows/wave). Block = in-block pair {i, 31-i}:
// phase A = tile pairi (pairi+1 KV-iters), phase B = tile 31-pairi
// (32-pairi iters) -> EVERY block exactly 33 iters (explicit balance,
// no co-residency assumption). Grid 16x64 = 1024 blocks = 4/CU (LDS-limited).
// ---------------------------------------------------------------------------
__global__ __launch_bounds__(256) void attn(
    const __bf16* __restrict__ Q, const __bf16* __restrict__ K,
    const __bf16* __restrict__ Vt, __bf16* __restrict__ Y) {
  __shared__ __align__(16) __bf16 Ks[2][64 * 72];
  __shared__ __align__(16) __bf16 Vs[2][64 * 72];   // [d][key]

  const int tid = threadIdx.x, w = tid >> 6, lane = tid & 63;
  const int l15 = lane & 15, quad = lane >> 4;
  const int bh = blockIdx.y;
  const int pairi = blockIdx.x;                      // 0..15

  const __bf16* Qbh = Q + (size_t)bh * T_SZ * HD;
  const __bf16* Kbh = K + (size_t)bh * T_SZ * HD;
  const __bf16* Vbh = Vt + (size_t)bh * HD * T_SZ;

  const int srow = tid >> 2;          // 0..63
  const int scol = (tid & 3) * 8;     // 0,8,16,24
  const int b = bh >> 4, h = bh & 15;

  for (int ph = 0; ph < 2; ph++) {
    const int tq = ph ? (31 - pairi) : pairi;
    const int q0 = tq * 64;
    const int niter = tq + 1;

    __syncthreads();   // prior phase fully done with LDS
    // prologue: stage KV tile 0 into buffer 0
    for (int p = 0; p < 2; p++) {
      int c = scol + p * 32;
      *(bf16x8*)(Ks[0] + srow * 72 + c) = *(const bf16x8*)(Kbh + (size_t)srow * HD + c);
      *(bf16x8*)(Vs[0] + srow * 72 + c) = *(const bf16x8*)(Vbh + (size_t)srow * T_SZ + c);
    }

    // Q fragments (B-operand: n=l15->q, k=quad*8+j->d); 16 q-rows per wave
    bf16x8 aq[2];
    for (int kc = 0; kc < 2; kc++)
      aq[kc] = *(const bf16x8*)(
          Qbh + (size_t)(q0 + w * 16 + l15) * HD + kc * 32 + quad * 8);

    f32x4 acco[4];     // O^T tiles [d16 x q16]: row d=quad*4+r, col q=l15
    for (int dt = 0; dt < 4; dt++) acco[dt] = (f32x4)0.f;
    float m_ = NEG_BIG, l_ = 0.f;

    for (int it = 0; it < niter; it++) {
      const int cur = it & 1;
      const int kv0 = it * 64;
      __syncthreads();

      // prefetch next KV tile into regs (overlaps compute)
      bf16x8 kn[2], vn[2];
      const bool havenext = (it + 1 < niter);
      if (havenext) {
        int kv1 = kv0 + 64;
        for (int p = 0; p < 2; p++) {
          int c = scol + p * 32;
          kn[p] = *(const bf16x8*)(Kbh + (size_t)(kv1 + srow) * HD + c);
          vn[p] = *(const bf16x8*)(Vbh + (size_t)srow * T_SZ + kv1 + c);
        }
      }

      const __bf16* Ksc = Ks[cur];
      const __bf16* Vsc = Vs[cur];

      // S^T = K Q^T : tiles [key16 x q16]; row key=quad*4+r, col q=l15
      f32x4 accs[4];
      for (int nt = 0; nt < 4; nt++) accs[nt] = (f32x4)0.f;
      for (int kc = 0; kc < 2; kc++)
        for (int nt = 0; nt < 4; nt++) {
          bf16x8 ak = *(const bf16x8*)(Ksc + (nt * 16 + l15) * 72 + kc * 32 + quad * 8);
          accs[nt] = __builtin_amdgcn_mfma_f32_16x16x32_bf16(
              ak, aq[kc], accs[nt], 0, 0, 0);
        }

      // causal mask (wave-uniform branch; only the diagonal tile triggers)
      if (kv0 + 63 > q0 + w * 16) {
        int qg = q0 + w * 16 + l15;
        for (int nt = 0; nt < 4; nt++) {
          int kg0 = kv0 + nt * 16 + quad * 4;
          for (int r = 0; r < 4; r++)
            if (kg0 + r > qg) accs[nt][r] = NEG_BIG;
        }
      }

      // online softmax over keys (in-reg tree + cross-quad shuffles)
      float a0 = fmaxf(fmaxf(accs[0][0], accs[0][1]), fmaxf(accs[0][2], accs[0][3]));
      float a1 = fmaxf(fmaxf(accs[1][0], accs[1][1]), fmaxf(accs[1][2], accs[1][3]));
      float a2 = fmaxf(fmaxf(accs[2][0], accs[2][1]), fmaxf(accs[2][2], accs[2][3]));
      float a3 = fmaxf(fmaxf(accs[3][0], accs[3][1]), fmaxf(accs[3][2], accs[3][3]));
      float mloc = fmaxf(fmaxf(a0, a1), fmaxf(a2, a3));
      for (int off = 16; off < 64; off <<= 1)
        mloc = fmaxf(mloc, __shfl_xor(mloc, off));
      float mnew = fmaxf(m_, mloc);
      float alpha = exp2f(m_ - mnew);
      m_ = mnew;
      float rs = 0.f;

      // P^T = exp2(S^T - m): stays in regs as x16 B-operand fragments
      bf16x4 pf[4];
      for (int nt = 0; nt < 4; nt++)
        for (int r = 0; r < 4; r++) {
          float p = exp2f(accs[nt][r] - m_);
          rs += p;
          pf[nt][r] = (__bf16)p;
        }
      for (int off = 16; off < 64; off <<= 1) rs += __shfl_xor(rs, off);
      l_ = l_ * alpha + rs;
      for (int dt = 0; dt < 4; dt++)
        for (int r = 0; r < 4; r++) acco[dt][r] *= alpha;

      // O^T += V^T P^T  (x16 MFMA; A from Vs, B from regs)
      for (int nt = 0; nt < 4; nt++)
        for (int dt = 0; dt < 4; dt++) {
          bf16x4 av = *(const bf16x4*)(Vsc + (dt * 16 + l15) * 72 + nt * 16 + quad * 4);
          acco[dt] = __builtin_amdgcn_mfma_f32_16x16x16bf16_1k(
              *(const s16x4*)&av, *(const s16x4*)&pf[nt], acco[dt], 0, 0, 0);
        }

      // stage prefetched tile into the other buffer
      if (havenext) {
        int nb = cur ^ 1;
        for (int p = 0; p < 2; p++) {
          int c = scol + p * 32;
          *(bf16x8*)(Ks[nb] + srow * 72 + c) = kn[p];
          *(bf16x8*)(Vs[nb] + srow * 72 + c) = vn[p];
        }
      }
    }

    // epilogue: O^T -> Y [B*T, 1024], 8B stores (4 consecutive d)
    {
      float rcp = 1.f / l_;
      int qg = q0 + w * 16 + l15;
      size_t base = ((size_t)(b * T_SZ + qg)) * CD + h * HD + quad * 4;
      for (int dt = 0; dt < 4; dt++) {
        bf16x4 o;
        for (int r = 0; r < 4; r++) o[r] = (__bf16)(acco[dt][r] * rcp);
        *(bf16x4*)(Y + base + dt * 16) = o;
      }
    }
  }
}

// ---------------------------------------------------------------------------
extern "C" void kernel_launch(void* const* d_in, const int* in_sizes, int n_in,
                              void* d_out, int out_size, void* d_ws, size_t ws_size,
                              hipStream_t stream) {
  (void)in_sizes; (void)n_in; (void)out_size; (void)ws_size;
  const void* x  = d_in[0];
  const void* Wq = d_in[2];
  const void* bq = d_in[3];
  const void* Wk = d_in[4];
  const void* bk = d_in[5];
  const void* Wv = d_in[6];
  const void* bv = d_in[7];
  const void* Wo = d_in[8];
  const void* bo = d_in[9];

  char* ws = (char*)d_ws;
  const size_t MB = 1024 * 1024;
  __bf16* WqkvT = (__bf16*)(ws + 0 * MB);          // [3072, 1024]
  __bf16* WoT   = (__bf16*)(ws + 6 * MB);
  __bf16* bqkvc = (__bf16*)(ws + 8 * MB);          // [3072]
  __bf16* boc   = (__bf16*)(ws + 8 * MB + 8192);
  int*    flag  = (int*)   (ws + 8 * MB + 65536);
  __bf16* xc    = (__bf16*)(ws + 9 * MB);          // [8192,1024]; reused as Yb
  __bf16* Qb    = (__bf16*)(ws + 25 * MB);         // [B*H,T,64] pre-scaled
  __bf16* Kb    = (__bf16*)(ws + 41 * MB);
  __bf16* Vt_g  = (__bf16*)(ws + 57 * MB);         // [B*H,64,T]
  __bf16* Yb    = xc;                              // xc dead after QKV GEMM

  dim3 tb(256);
  detect_dtype<<<1, tb, 0, stream>>>((const uint32_t*)x, flag);

  conv_in<<<4096, tb, 0, stream>>>(x, flag, xc, MROWS * CD / 8);
  Ptr4 pb = {{bq, bk, bv, bo}, {bqkvc, bqkvc + CD, bqkvc + 2 * CD, boc}};
  conv_b4<<<4, tb, 0, stream>>>(pb, flag);
  Ptr4 pw = {{Wq, Wk, Wv, Wo},
             {WqkvT, WqkvT + (size_t)CD * CD, WqkvT + 2 * (size_t)CD * CD, WoT}};
  transpose_conv4<<<dim3(16, 16, 4), tb, 0, stream>>>(pw, flag);

  gemm_qkv<<<dim3(24, MROWS / 128), tb, 0, stream>>>(xc, WqkvT, bqkvc, Qb, Kb, Vt_g);

  attn<<<dim3(16, B_SZ * NH), tb, 0, stream>>>(Qb, Kb, Vt_g, Yb);

  gemm_out<<<dim3(CD / 128, MROWS / 128), tb, 0, stream>>>(Yb, WoT, boc, d_out, flag);
}

// Round 8
// 326.773 us; speedup vs baseline: 1.2422x; 1.0593x over previous
//
#include <hip/hip_runtime.h>
#include <cstdint>
#include <cstddef>

#define B_SZ 4
#define T_SZ 2048
#define NH 16
#define HD 64
#define CD 1024
#define MROWS (B_SZ*T_SZ)
#define NEG_BIG (-1e30f)
// 0.125 (1/sqrt(64)) * log2(e): fold softmax base-2 conversion into Q prescale
#define Q_SCALE 0.180336880f

typedef __bf16 bf16x8 __attribute__((ext_vector_type(8)));
typedef __bf16 bf16x4 __attribute__((ext_vector_type(4)));
typedef short s16x4 __attribute__((ext_vector_type(4)));
typedef float f32x4 __attribute__((ext_vector_type(4)));

typedef __attribute__((address_space(3))) void* as3p;
typedef const __attribute__((address_space(1))) void* as1p;

__device__ __forceinline__ void glds16(const void* g, void* l) {
  __builtin_amdgcn_global_load_lds((as1p)g, (as3p)l, 16, 0, 0);
}

// ---------------------------------------------------------------------------
// Dtype discriminator (fp32 vs bf16 input encoding). flag=1 -> bf16.
// ---------------------------------------------------------------------------
__global__ __launch_bounds__(256) void detect_dtype(const uint32_t* __restrict__ x,
                                                    int* __restrict__ flag) {
  __shared__ int cnt[256];
  const int t = threadIdx.x;
  int c = 0;
  for (int i = 0; i < 4; i++) {
    uint32_t w = x[t * 4 + i];
    uint32_t e = (w >> 7) & 0xFF;
    c += (e >= 100 && e <= 140) ? 1 : 0;
  }
  cnt[t] = c;
  __syncthreads();
  for (int s = 128; s > 0; s >>= 1) {
    if (t < s) cnt[t] += cnt[t + s];
    __syncthreads();
  }
  if (t == 0) flag[0] = (cnt[0] > 700) ? 1 : 0;
}

__device__ __forceinline__ bf16x8 cvt8(const void* src, int isbf, size_t i8) {
  bf16x8 o;
  if (isbf) {
    o = ((const bf16x8*)src)[i8];
  } else {
    const float4* s = (const float4*)((const float*)src + i8 * 8);
    float4 a = s[0], b = s[1];
    o[0] = (__bf16)a.x; o[1] = (__bf16)a.y; o[2] = (__bf16)a.z; o[3] = (__bf16)a.w;
    o[4] = (__bf16)b.x; o[5] = (__bf16)b.y; o[6] = (__bf16)b.z; o[7] = (__bf16)b.w;
  }
  return o;
}

__global__ __launch_bounds__(256) void conv_in(const void* __restrict__ src,
                                               const int* __restrict__ flag,
                                               __bf16* __restrict__ dst, int n8) {
  int i = blockIdx.x * 256 + threadIdx.x;
  if (i >= n8) return;
  ((bf16x8*)dst)[i] = cvt8(src, flag[0], i);
}

struct Ptr4 { const void* s[4]; __bf16* d[4]; };

__global__ __launch_bounds__(256) void conv_b4(Ptr4 p, const int* __restrict__ flag) {
  int i = threadIdx.x;
  if (i >= CD / 8) return;
  int which = blockIdx.x;
  ((bf16x8*)p.d[which])[i] = cvt8(p.s[which], flag[0], i);
}

// 4 weight matrices 1024x1024 -> transposed canonical bf16 (z selects)
__global__ __launch_bounds__(256) void transpose_conv4(Ptr4 p,
                                                       const int* __restrict__ flag) {
  __shared__ __align__(16) __bf16 tile[64 * 72];
  const void* W = p.s[blockIdx.z];
  __bf16* WT = p.d[blockIdx.z];
  const int t = threadIdx.x;
  const int r0 = blockIdx.y * 64, c0 = blockIdx.x * 64;
  const int rr = t >> 3, c8 = (t & 7) * 8;
  const int isbf = flag[0];
  for (int pp = 0; pp < 2; pp++) {
    int r = pp * 32 + rr;
    *(bf16x8*)(tile + r * 72 + c8) =
        cvt8(W, isbf, ((size_t)(r0 + r) * CD + c0 + c8) / 8);
  }
  __syncthreads();
  for (int pp = 0; pp < 2; pp++) {
    int cc = pp * 32 + rr;
    bf16x8 o;
    for (int j = 0; j < 8; j++) o[j] = tile[(c8 + j) * 72 + cc];
    *(bf16x8*)(WT + (size_t)(c0 + cc) * CD + r0 + c8) = o;
  }
}

// ---------------------------------------------------------------------------
// Fused QKV GEMM: C[8192, 3072] = x @ [WqT;WkT;WvT]^T + bias.
// Epilogue routes by col segment: 0-1023 -> Qb (scaled, [B,H,T,64]),
// 1024-2047 -> Kb ([B,H,T,64]), 2048-3071 -> Vt ([B*H, 64, T]).
// ---------------------------------------------------------------------------
__global__ __launch_bounds__(256) void gemm_qkv(
    const __bf16* __restrict__ A, const __bf16* __restrict__ BT,
    const __bf16* __restrict__ bias,
    __bf16* __restrict__ Qb, __bf16* __restrict__ Kb, __bf16* __restrict__ Vt) {
  __shared__ __align__(16) __bf16 As[128 * 64];
  __shared__ __align__(16) __bf16 Bs[128 * 64];
  const int tid = threadIdx.x;
  const int w = tid >> 6, lane = tid & 63;
  const int l15 = lane & 15, quad = lane >> 4;
  const int wm = w & 1, wn = w >> 1;
  const int bm = blockIdx.y, bn = blockIdx.x;

  f32x4 acc[4][4];
  for (int i = 0; i < 4; i++)
    for (int j = 0; j < 4; j++) acc[i][j] = (f32x4)0.f;

  const int srow = lane >> 3, scol = (lane & 7) * 8;
  const __bf16* Abase = A + (size_t)(bm * 128) * CD;
  const __bf16* Bbase = BT + (size_t)(bn * 128) * CD;

  for (int k0 = 0; k0 < CD; k0 += 64) {
    __syncthreads();
    for (int p = 0; p < 4; p++) {
      int seg = p * 4 + w;
      int row = seg * 8 + srow;
      glds16(Abase + (size_t)row * CD + k0 + scol, (char*)As + seg * 1024);
      glds16(Bbase + (size_t)row * CD + k0 + scol, (char*)Bs + seg * 1024);
    }
    __syncthreads();
    for (int kc = 0; kc < 2; kc++) {
      const int koff = kc * 32 + quad * 8;
      bf16x8 af[4], bfr[4];
      for (int mt = 0; mt < 4; mt++)
        af[mt] = *(const bf16x8*)(As + (wm * 64 + mt * 16 + l15) * 64 + koff);
      for (int nt = 0; nt < 4; nt++)
        bfr[nt] = *(const bf16x8*)(Bs + (wn * 64 + nt * 16 + l15) * 64 + koff);
      for (int mt = 0; mt < 4; mt++)
        for (int nt = 0; nt < 4; nt++)
          acc[mt][nt] = __builtin_amdgcn_mfma_f32_16x16x32_bf16(
              af[mt], bfr[nt], acc[mt][nt], 0, 0, 0);
    }
  }

  for (int nt = 0; nt < 4; nt++) {
    int col = bn * 128 + wn * 64 + nt * 16 + l15;
    int seg = col >> 10;            // 0=Q 1=K 2=V (uniform per nt)
    int c = col & 1023, h = c >> 6, d = c & 63;
    float bv = (float)bias[col];
    for (int mt = 0; mt < 4; mt++) {
      int row0 = bm * 128 + wm * 64 + mt * 16 + quad * 4;
      int b = row0 >> 11, tok0 = row0 & 2047;
      if (seg == 2) {
        bf16x4 o;
        for (int r = 0; r < 4; r++) o[r] = (__bf16)(acc[mt][nt][r] + bv);
        *(bf16x4*)(Vt + ((size_t)((b << 4) + h) * HD + d) * T_SZ + tok0) = o;
      } else {
        __bf16* dst = (seg == 0) ? Qb : Kb;
        float sc = (seg == 0) ? Q_SCALE : 1.f;
        for (int r = 0; r < 4; r++) {
          float v = (acc[mt][nt][r] + bv) * sc;
          dst[((size_t)(b * NH + h) * T_SZ + tok0 + r) * HD + d] = (__bf16)v;
        }
      }
    }
  }
}

// ---------------------------------------------------------------------------
// Out-proj GEMM: d_out[8192,1024] = Yb @ WoT^T + bo, output dtype per flag.
// ---------------------------------------------------------------------------
__global__ __launch_bounds__(256) void gemm_out(
    const __bf16* __restrict__ A, const __bf16* __restrict__ BT,
    const __bf16* __restrict__ bias, void* __restrict__ Out,
    const int* __restrict__ flag) {
  __shared__ __align__(16) __bf16 As[128 * 64];
  __shared__ __align__(16) __bf16 Bs[128 * 64];
  const int tid = threadIdx.x;
  const int w = tid >> 6, lane = tid & 63;
  const int l15 = lane & 15, quad = lane >> 4;
  const int wm = w & 1, wn = w >> 1;
  const int bm = blockIdx.y, bn = blockIdx.x;

  f32x4 acc[4][4];
  for (int i = 0; i < 4; i++)
    for (int j = 0; j < 4; j++) acc[i][j] = (f32x4)0.f;

  const int srow = lane >> 3, scol = (lane & 7) * 8;
  const __bf16* Abase = A + (size_t)(bm * 128) * CD;
  const __bf16* Bbase = BT + (size_t)(bn * 128) * CD;

  for (int k0 = 0; k0 < CD; k0 += 64) {
    __syncthreads();
    for (int p = 0; p < 4; p++) {
      int seg = p * 4 + w;
      int row = seg * 8 + srow;
      glds16(Abase + (size_t)row * CD + k0 + scol, (char*)As + seg * 1024);
      glds16(Bbase + (size_t)row * CD + k0 + scol, (char*)Bs + seg * 1024);
    }
    __syncthreads();
    for (int kc = 0; kc < 2; kc++) {
      const int koff = kc * 32 + quad * 8;
      bf16x8 af[4], bfr[4];
      for (int mt = 0; mt < 4; mt++)
        af[mt] = *(const bf16x8*)(As + (wm * 64 + mt * 16 + l15) * 64 + koff);
      for (int nt = 0; nt < 4; nt++)
        bfr[nt] = *(const bf16x8*)(Bs + (wn * 64 + nt * 16 + l15) * 64 + koff);
      for (int mt = 0; mt < 4; mt++)
        for (int nt = 0; nt < 4; nt++)
          acc[mt][nt] = __builtin_amdgcn_mfma_f32_16x16x32_bf16(
              af[mt], bfr[nt], acc[mt][nt], 0, 0, 0);
    }
  }

  const int isbf = flag[0];
  for (int nt = 0; nt < 4; nt++) {
    int col = bn * 128 + wn * 64 + nt * 16 + l15;
    float bv = (float)bias[col];
    for (int mt = 0; mt < 4; mt++) {
      int row0 = bm * 128 + wm * 64 + mt * 16 + quad * 4;
      if (isbf) {
        for (int r = 0; r < 4; r++)
          ((__bf16*)Out)[(size_t)(row0 + r) * CD + col] =
              (__bf16)(acc[mt][nt][r] + bv);
      } else {
        for (int r = 0; r < 4; r++)
          ((float*)Out)[(size_t)(row0 + r) * CD + col] = acc[mt][nt][r] + bv;
      }
    }
  }
}

// ---------------------------------------------------------------------------
// Flash attention, causal, transposed-S. Q pre-scaled by 0.125*log2e.
// Q/K: [B*H, T, 64]; Vt: [B*H, 64, T].
// 512-thread blocks (8 waves). Q-tile 256 rows (32 q/wave as 2 independent
// 16-q streams). Block = in-block pair {i, 7-i}: (4i+4) + (4(7-i)+4) = 36
// KV-iters for EVERY block. Grid 4x64 = 256 blocks = 1/CU, 8 waves/CU.
// KV logical traffic: 144 tiles/bh (half of q-tile-128 config).
// ---------------------------------------------------------------------------
__global__ __launch_bounds__(512) void attn(
    const __bf16* __restrict__ Q, const __bf16* __restrict__ K,
    const __bf16* __restrict__ Vt, __bf16* __restrict__ Y) {
  __shared__ __align__(16) __bf16 Ks[2][64 * 72];
  __shared__ __align__(16) __bf16 Vs[2][64 * 72];   // [d][key]

  const int tid = threadIdx.x, w = tid >> 6, lane = tid & 63;
  const int l15 = lane & 15, quad = lane >> 4;
  const int bh = blockIdx.y;
  const int pairi = blockIdx.x;                      // 0..3

  const __bf16* Qbh = Q + (size_t)bh * T_SZ * HD;
  const __bf16* Kbh = K + (size_t)bh * T_SZ * HD;
  const __bf16* Vbh = Vt + (size_t)bh * HD * T_SZ;

  const int srow = tid >> 3;          // 0..63
  const int scol = (tid & 7) * 8;     // 0..56
  const int b = bh >> 4, h = bh & 15;

  for (int ph = 0; ph < 2; ph++) {
    const int tq = ph ? (7 - pairi) : pairi;
    const int q0 = tq * 256;
    const int niter = 4 * tq + 4;

    __syncthreads();   // prior phase fully done with LDS
    // prologue: stage KV tile 0 into buffer 0 (one 16B store per thread/array)
    *(bf16x8*)(Ks[0] + srow * 72 + scol) =
        *(const bf16x8*)(Kbh + (size_t)srow * HD + scol);
    *(bf16x8*)(Vs[0] + srow * 72 + scol) =
        *(const bf16x8*)(Vbh + (size_t)srow * T_SZ + scol);

    // Q fragments (B-operand: n=l15->q, k=quad*8+j->d); 2 streams of 16 q
    bf16x8 aq[2][2];
    for (int mt = 0; mt < 2; mt++)
      for (int kc = 0; kc < 2; kc++)
        aq[mt][kc] = *(const bf16x8*)(
            Qbh + (size_t)(q0 + w * 32 + mt * 16 + l15) * HD + kc * 32 + quad * 8);

    f32x4 acco[2][4];   // O^T tiles [d16 x q16]: row d=quad*4+r, col q=l15
    for (int mt = 0; mt < 2; mt++)
      for (int dt = 0; dt < 4; dt++) acco[mt][dt] = (f32x4)0.f;
    float m_[2], l_[2];
    for (int mt = 0; mt < 2; mt++) { m_[mt] = NEG_BIG; l_[mt] = 0.f; }

    for (int it = 0; it < niter; it++) {
      const int cur = it & 1;
      const int kv0 = it * 64;
      __syncthreads();

      // prefetch next KV tile into regs (overlaps compute)
      bf16x8 kn, vn;
      const bool havenext = (it + 1 < niter);
      if (havenext) {
        int kv1 = kv0 + 64;
        kn = *(const bf16x8*)(Kbh + (size_t)(kv1 + srow) * HD + scol);
        vn = *(const bf16x8*)(Vbh + (size_t)srow * T_SZ + kv1 + scol);
      }

      const __bf16* Ksc = Ks[cur];
      const __bf16* Vsc = Vs[cur];

      // S^T = K Q^T : tiles [key16 x q16]; row key=quad*4+r, col q=l15
      f32x4 accs[2][4];
      for (int mt = 0; mt < 2; mt++)
        for (int nt = 0; nt < 4; nt++) accs[mt][nt] = (f32x4)0.f;
      for (int kc = 0; kc < 2; kc++)
        for (int nt = 0; nt < 4; nt++) {
          bf16x8 ak = *(const bf16x8*)(Ksc + (nt * 16 + l15) * 72 + kc * 32 + quad * 8);
          for (int mt = 0; mt < 2; mt++)
            accs[mt][nt] = __builtin_amdgcn_mfma_f32_16x16x32_bf16(
                ak, aq[mt][kc], accs[mt][nt], 0, 0, 0);
        }

      // causal mask (per-stream wave-uniform branch; only diagonal tiles)
      for (int mt = 0; mt < 2; mt++) {
        if (kv0 + 63 > q0 + w * 32 + mt * 16) {
          int qg = q0 + w * 32 + mt * 16 + l15;
          for (int nt = 0; nt < 4; nt++) {
            int kg0 = kv0 + nt * 16 + quad * 4;
            for (int r = 0; r < 4; r++)
              if (kg0 + r > qg) accs[mt][nt][r] = NEG_BIG;
          }
        }
      }

      // online softmax over keys (in-reg tree + cross-quad shuffles)
      float mloc[2], alpha[2], rs[2];
      for (int mt = 0; mt < 2; mt++) {
        float a0 = fmaxf(fmaxf(accs[mt][0][0], accs[mt][0][1]),
                         fmaxf(accs[mt][0][2], accs[mt][0][3]));
        float a1 = fmaxf(fmaxf(accs[mt][1][0], accs[mt][1][1]),
                         fmaxf(accs[mt][1][2], accs[mt][1][3]));
        float a2 = fmaxf(fmaxf(accs[mt][2][0], accs[mt][2][1]),
                         fmaxf(accs[mt][2][2], accs[mt][2][3]));
        float a3 = fmaxf(fmaxf(accs[mt][3][0], accs[mt][3][1]),
                         fmaxf(accs[mt][3][2], accs[mt][3][3]));
        mloc[mt] = fmaxf(fmaxf(a0, a1), fmaxf(a2, a3));
      }
      for (int off = 16; off < 64; off <<= 1)
        for (int mt = 0; mt < 2; mt++)
          mloc[mt] = fmaxf(mloc[mt], __shfl_xor(mloc[mt], off));
      for (int mt = 0; mt < 2; mt++) {
        float mnew = fmaxf(m_[mt], mloc[mt]);
        alpha[mt] = exp2f(m_[mt] - mnew);
        m_[mt] = mnew;
        rs[mt] = 0.f;
      }

      // P^T = exp2(S^T - m): stays in regs as x16 B-operand fragments
      bf16x4 pf[2][4];
      for (int mt = 0; mt < 2; mt++)
        for (int nt = 0; nt < 4; nt++)
          for (int r = 0; r < 4; r++) {
            float p = exp2f(accs[mt][nt][r] - m_[mt]);
            rs[mt] += p;
            pf[mt][nt][r] = (__bf16)p;
          }
      for (int off = 16; off < 64; off <<= 1)
        for (int mt = 0; mt < 2; mt++) rs[mt] += __shfl_xor(rs[mt], off);
      for (int mt = 0; mt < 2; mt++) l_[mt] = l_[mt] * alpha[mt] + rs[mt];
      for (int mt = 0; mt < 2; mt++)
        for (int dt = 0; dt < 4; dt++)
          for (int r = 0; r < 4; r++) acco[mt][dt][r] *= alpha[mt];

      // O^T += V^T P^T  (x16 MFMA; A from Vs, B from regs)
      for (int nt = 0; nt < 4; nt++)
        for (int dt = 0; dt < 4; dt++) {
          bf16x4 av = *(const bf16x4*)(Vsc + (dt * 16 + l15) * 72 + nt * 16 + quad * 4);
          for (int mt = 0; mt < 2; mt++)
            acco[mt][dt] = __builtin_amdgcn_mfma_f32_16x16x16bf16_1k(
                *(const s16x4*)&av, *(const s16x4*)&pf[mt][nt], acco[mt][dt], 0, 0, 0);
        }

      // stage prefetched tile into the other buffer
      if (havenext) {
        int nb = cur ^ 1;
        *(bf16x8*)(Ks[nb] + srow * 72 + scol) = kn;
        *(bf16x8*)(Vs[nb] + srow * 72 + scol) = vn;
      }
    }

    // epilogue: O^T -> Y [B*T, 1024], 8B stores (4 consecutive d)
    for (int mt = 0; mt < 2; mt++) {
      float rcp = 1.f / l_[mt];
      int qg = q0 + w * 32 + mt * 16 + l15;
      size_t base = ((size_t)(b * T_SZ + qg)) * CD + h * HD + quad * 4;
      for (int dt = 0; dt < 4; dt++) {
        bf16x4 o;
        for (int r = 0; r < 4; r++) o[r] = (__bf16)(acco[mt][dt][r] * rcp);
        *(bf16x4*)(Y + base + dt * 16) = o;
      }
    }
  }
}

// ---------------------------------------------------------------------------
extern "C" void kernel_launch(void* const* d_in, const int* in_sizes, int n_in,
                              void* d_out, int out_size, void* d_ws, size_t ws_size,
                              hipStream_t stream) {
  (void)in_sizes; (void)n_in; (void)out_size; (void)ws_size;
  const void* x  = d_in[0];
  const void* Wq = d_in[2];
  const void* bq = d_in[3];
  const void* Wk = d_in[4];
  const void* bk = d_in[5];
  const void* Wv = d_in[6];
  const void* bv = d_in[7];
  const void* Wo = d_in[8];
  const void* bo = d_in[9];

  char* ws = (char*)d_ws;
  const size_t MB = 1024 * 1024;
  __bf16* WqkvT = (__bf16*)(ws + 0 * MB);          // [3072, 1024]
  __bf16* WoT   = (__bf16*)(ws + 6 * MB);
  __bf16* bqkvc = (__bf16*)(ws + 8 * MB);          // [3072]
  __bf16* boc   = (__bf16*)(ws + 8 * MB + 8192);
  int*    flag  = (int*)   (ws + 8 * MB + 65536);
  __bf16* xc    = (__bf16*)(ws + 9 * MB);          // [8192,1024]; reused as Yb
  __bf16* Qb    = (__bf16*)(ws + 25 * MB);         // [B*H,T,64] pre-scaled
  __bf16* Kb    = (__bf16*)(ws + 41 * MB);
  __bf16* Vt_g  = (__bf16*)(ws + 57 * MB);         // [B*H,64,T]
  __bf16* Yb    = xc;                              // xc dead after QKV GEMM

  dim3 tb(256);
  detect_dtype<<<1, tb, 0, stream>>>((const uint32_t*)x, flag);

  conv_in<<<4096, tb, 0, stream>>>(x, flag, xc, MROWS * CD / 8);
  Ptr4 pb = {{bq, bk, bv, bo}, {bqkvc, bqkvc + CD, bqkvc + 2 * CD, boc}};
  conv_b4<<<4, tb, 0, stream>>>(pb, flag);
  Ptr4 pw = {{Wq, Wk, Wv, Wo},
             {WqkvT, WqkvT + (size_t)CD * CD, WqkvT + 2 * (size_t)CD * CD, WoT}};
  transpose_conv4<<<dim3(16, 16, 4), tb, 0, stream>>>(pw, flag);

  gemm_qkv<<<dim3(24, MROWS / 128), tb, 0, stream>>>(xc, WqkvT, bqkvc, Qb, Kb, Vt_g);

  attn<<<dim3(4, B_SZ * NH), dim3(512), 0, stream>>>(Qb, Kb, Vt_g, Yb);

  gemm_out<<<dim3(CD / 128, MROWS / 128), tb, 0, stream>>>(Yb, WoT, boc, d_out, flag);
}